// Round 3
// baseline (1030.885 us; speedup 1.0000x reference)
//
#include <hip/hip_runtime.h>

constexpr int N_NODES = 50000;
constexpr int E_EDGES = 1600000;
constexpr int NH      = N_NODES * 32;   // 1,600,000
constexpr float BN_EPS = 1e-5f;
constexpr int NPAD    = 50016;

// ---------------------------------------------------------------- zero scratch
__global__ void zero_kernel(float4* __restrict__ p, int n4) {
    int i = blockIdx.x * blockDim.x + threadIdx.x;
    if (i < n4) p[i] = make_float4(0.f, 0.f, 0.f, 0.f);
}

// ---------------------------------------------------------------- CSR build
__global__ void hist_kernel(const int* __restrict__ ei, int* __restrict__ counts) {
    int e = blockIdx.x * blockDim.x + threadIdx.x;
    if (e < E_EDGES) atomicAdd(&counts[ei[E_EDGES + e]], 1);
}

__device__ inline int block_excl_scan(int v, int* s) {
    int t = threadIdx.x;
    s[t] = v;
    __syncthreads();
    for (int d = 1; d < 256; d <<= 1) {
        int x = (t >= d) ? s[t - d] : 0;
        __syncthreads();
        s[t] += x;
        __syncthreads();
    }
    return s[t] - v;   // exclusive
}

__global__ void scan1_kernel(const int* __restrict__ counts, int* __restrict__ bsum) {
    int i = blockIdx.x * 256 + threadIdx.x;
    int v = (i < N_NODES) ? counts[i] : 0;
#pragma unroll
    for (int o = 32; o > 0; o >>= 1) v += __shfl_down(v, o);
    __shared__ int s[4];
    int wave = threadIdx.x >> 6, lane = threadIdx.x & 63;
    if (lane == 0) s[wave] = v;
    __syncthreads();
    if (threadIdx.x == 0) bsum[blockIdx.x] = s[0] + s[1] + s[2] + s[3];
}

__global__ void scan2_kernel(int* __restrict__ bsum) {   // 1 block
    __shared__ int s[256];
    int t = threadIdx.x;
    int v = (t < 196) ? bsum[t] : 0;
    int excl = block_excl_scan(v, s);
    if (t < 196) bsum[t] = excl;
}

__global__ void scan3_kernel(const int* __restrict__ counts, const int* __restrict__ bsum,
                             int* __restrict__ off, int* __restrict__ cursor) {
    __shared__ int s[256];
    int i = blockIdx.x * 256 + threadIdx.x;
    int v = (i < N_NODES) ? counts[i] : 0;
    int excl = block_excl_scan(v, s) + bsum[blockIdx.x];
    if (i < N_NODES) { off[i] = excl; cursor[i] = excl; }
    if (i == N_NODES - 1) off[N_NODES] = excl + v;   // == E
}

// one interleaved int2 {tagged_src, w_bits} per edge: single 8B scattered store
__global__ void place_kernel(const int* __restrict__ ei, const float* __restrict__ ew,
                             int* __restrict__ cursor, int2* __restrict__ ep) {
    int e = blockIdx.x * blockDim.x + threadIdx.x;
    if (e < E_EDGES) {
        int src = ei[e];
        int dst = ei[E_EDGES + e];
        int pos = atomicAdd(&cursor[dst], 1);
        ep[pos] = make_int2(src | ((src == dst) ? 0x80000000 : 0),
                            __float_as_int(ew[e]));
    }
}

// ---------------------------------------------------------------- fused gather:
// BN (per-lane scale/shift) + weighted neighbor sum + 32x32 W-contraction + relu.
// 32 lanes per node (c = lane&31), 8 nodes per 256-thread block. Full 32-edge
// batches run unmasked with unroll 8 (8 independent row-gathers in flight).
__global__ void gather_kernel(const float* __restrict__ x,
                              const float* __restrict__ gamma,
                              const float* __restrict__ beta,
                              const float* __restrict__ mean,
                              const float* __restrict__ var,
                              const int*   __restrict__ off,
                              const int2*  __restrict__ ep,
                              const float* __restrict__ W,
                              float* __restrict__ rres) {
    __shared__ float s_w0[1024], s_wsum[1024];
    int tid = threadIdx.x;
    for (int idx = tid; idx < 1024; idx += 256) {
        s_w0[idx]   = W[idx];
        s_wsum[idx] = W[1024 + idx] + W[2048 + idx];
    }
    __syncthreads();

    int n     = blockIdx.x * 8 + (tid >> 5);  // 6250*8 = 50000 exactly
    int c     = tid & 31;
    int gbase = tid & 32;                     // group base lane within the wave

    float sc = gamma[c] * rsqrtf(var[c] + BN_EPS);
    float sh = beta[c] - mean[c] * sc;

    int e0 = off[n];
    int nb = off[n + 1] - e0;
    const int2* e2 = ep + e0;
    float acc = 0.f, acc0 = 0.f;

    int base = 0;
    for (; base + 32 <= nb; base += 32) {       // full batches, unmasked
        int2 p = e2[base + c];
        int sw = p.x; float wv = __int_as_float(p.y);
#pragma unroll 8
        for (int j = 0; j < 32; j++) {
            int   swj = __shfl(sw, gbase + j);
            float wj  = __shfl(wv, gbase + j);
            float v   = fmaf(x[(swj & 0x7fffffff) * 32 + c], sc, sh);
            acc = fmaf(wj, v, acc);
            if (swj < 0) acc0 += v;
        }
    }
    int rem = nb - base;
    if (rem > 0) {                               // tail batch
        int sw = 0; float wv = 0.f;
        if (c < rem) { int2 p = e2[base + c]; sw = p.x; wv = __int_as_float(p.y); }
        for (int j = 0; j < rem; j++) {
            int   swj = __shfl(sw, gbase + j);
            float wj  = __shfl(wv, gbase + j);
            float v   = fmaf(x[(swj & 0x7fffffff) * 32 + c], sc, sh);
            acc = fmaf(wj, v, acc);
            if (swj < 0) acc0 += v;
        }
    }
    // result[n,h] = relu(sum_c acc_c*Wsum[c,h] + acc0_c*W0[c,h]), h = c
    float r = 0.f;
#pragma unroll
    for (int cc = 0; cc < 32; cc++) {
        float a  = __shfl(acc,  gbase + cc);
        float a0 = __shfl(acc0, gbase + cc);
        r = fmaf(a,  s_wsum[cc * 32 + c], r);
        r = fmaf(a0, s_w0  [cc * 32 + c], r);
    }
    rres[n * 32 + c] = fmaxf(r, 0.f);
}

// ---------------------------------------------------------------- fc1: [1,NH] @ [NH,64]^T
// grid (625, 4): blockIdx.x = 2560-float chunk, blockIdx.y = 16-row group.
// 4 waves/block, each wave owns 4 rows (2 at a time, proven VGPR~32 body).
// 2500 blocks ~ 10 blocks/CU -> latency hidden by occupancy, not per-thread ILP.
constexpr int CHUNK = 2560;   // 640 float4; NH/CHUNK = 625
__global__ void fc1_kernel(const float* __restrict__ r,
                           const float* __restrict__ w,
                           float* __restrict__ hacc) {
    __shared__ float4 s_r[640];
    int tid = threadIdx.x;
    size_t ib = (size_t)blockIdx.x * CHUNK;
    const float4* r4 = (const float4*)(r + ib);
    for (int i = tid; i < 640; i += 256) s_r[i] = r4[i];
    __syncthreads();

    int wave = tid >> 6, lane = tid & 63;
    int row0 = blockIdx.y * 16 + wave * 4;
    for (int jj = 0; jj < 4; jj += 2) {
        const float4* wa = (const float4*)(w + (size_t)(row0 + jj    ) * NH + ib);
        const float4* wb = (const float4*)(w + (size_t)(row0 + jj + 1) * NH + ib);
        float a0 = 0.f, a1 = 0.f;
#pragma unroll
        for (int k = 0; k < 10; k++) {
            float4 rv = s_r[lane + k * 64];
            float4 x0 = wa[lane + k * 64];
            float4 x1 = wb[lane + k * 64];
            a0 = fmaf(rv.x, x0.x, a0); a0 = fmaf(rv.y, x0.y, a0);
            a0 = fmaf(rv.z, x0.z, a0); a0 = fmaf(rv.w, x0.w, a0);
            a1 = fmaf(rv.x, x1.x, a1); a1 = fmaf(rv.y, x1.y, a1);
            a1 = fmaf(rv.z, x1.z, a1); a1 = fmaf(rv.w, x1.w, a1);
        }
#pragma unroll
        for (int o = 32; o > 0; o >>= 1) {
            a0 += __shfl_down(a0, o);
            a1 += __shfl_down(a1, o);
        }
        if (lane == 0) {
            atomicAdd(&hacc[row0 + jj    ], a0);
            atomicAdd(&hacc[row0 + jj + 1], a1);
        }
    }
}

// ---------------------------------------------------------------- head: relu + fc2
__global__ void head_kernel(const float* __restrict__ hacc,
                            const float* __restrict__ fc1_b,
                            const float* __restrict__ fc2_w,
                            const float* __restrict__ fc2_b,
                            float* __restrict__ out) {
    int j = threadIdx.x;   // 64 threads = 1 wave
    float hj = fmaxf(hacc[j] + fc1_b[j], 0.f);
#pragma unroll
    for (int k = 0; k < 2; k++) {
        float p = hj * fc2_w[k * 64 + j];
#pragma unroll
        for (int o = 32; o > 0; o >>= 1) p += __shfl_down(p, o);
        if (j == 0) out[k] = p + fc2_b[k];
    }
}

// ---------------------------------------------------------------- launch
extern "C" void kernel_launch(void* const* d_in, const int* in_sizes, int n_in,
                              void* d_out, int out_size, void* d_ws, size_t ws_size,
                              hipStream_t stream) {
    const float* x     = (const float*)d_in[0];
    const float* ew    = (const float*)d_in[1];
    const float* W     = (const float*)d_in[2];
    const float* gamma = (const float*)d_in[3];
    const float* beta  = (const float*)d_in[4];
    const float* mean  = (const float*)d_in[5];
    const float* var   = (const float*)d_in[6];
    const float* fc1_w = (const float*)d_in[7];
    const float* fc1_b = (const float*)d_in[8];
    const float* fc2_w = (const float*)d_in[9];
    const float* fc2_b = (const float*)d_in[10];
    const int*   ei    = (const int*)d_in[11];
    float* out = (float*)d_out;

    // ws layout (4B elems): hacc(64) | counts(NPAD) | off(NPAD) | cursor(NPAD)
    //                       | bsum(256) | ep(int2 x E) | rres(NH)   ~ 19.8 MB
    float* hacc   = (float*)d_ws;
    int*   counts = (int*)d_ws + 64;
    int*   off    = (int*)d_ws + 64 + NPAD;
    int*   cursor = (int*)d_ws + 64 + 2 * NPAD;
    int*   bsum   = (int*)d_ws + 64 + 3 * NPAD;
    int2*  ep     = (int2*)(bsum + 256);        // byte offset 601472, 8B-aligned
    float* rres   = (float*)(ep + E_EDGES);
    (void)ws_size; (void)in_sizes; (void)n_in; (void)out_size;

    {   // zero hacc + counts
        int n4 = (64 + NPAD) / 4;
        zero_kernel<<<(n4 + 255) / 256, 256, 0, stream>>>((float4*)d_ws, n4);
    }
    hist_kernel <<<(E_EDGES + 255) / 256, 256, 0, stream>>>(ei, counts);
    scan1_kernel<<<196, 256, 0, stream>>>(counts, bsum);
    scan2_kernel<<<1,   256, 0, stream>>>(bsum);
    scan3_kernel<<<196, 256, 0, stream>>>(counts, bsum, off, cursor);
    place_kernel<<<(E_EDGES + 255) / 256, 256, 0, stream>>>(ei, ew, cursor, ep);
    gather_kernel<<<N_NODES / 8, 256, 0, stream>>>(x, gamma, beta, mean, var,
                                                   off, ep, W, rres);
    fc1_kernel <<<dim3(625, 4), 256, 0, stream>>>(rres, fc1_w, hacc);
    head_kernel<<<1, 64, 0, stream>>>(hacc, fc1_b, fc2_w, fc2_b, out);
}

// Round 4
// 824.792 us; speedup vs baseline: 1.2499x; 1.2499x over previous
//
#include <hip/hip_runtime.h>

constexpr int N_NODES = 50000;
constexpr int E_EDGES = 1600000;
constexpr int NH      = N_NODES * 32;   // 1,600,000
constexpr float BN_EPS = 1e-5f;
constexpr int NPAD    = 50016;
constexpr int NBLK    = 625;            // fc1 chunk blocks

// ---------------------------------------------------------------- zero scratch
__global__ void zero_kernel(float4* __restrict__ p, int n4) {
    int i = blockIdx.x * blockDim.x + threadIdx.x;
    if (i < n4) p[i] = make_float4(0.f, 0.f, 0.f, 0.f);
}

// ---------------------------------------------------------------- CSR build
__global__ void hist_kernel(const int* __restrict__ ei, int* __restrict__ counts) {
    int e = blockIdx.x * blockDim.x + threadIdx.x;
    if (e < E_EDGES) atomicAdd(&counts[ei[E_EDGES + e]], 1);
}

__device__ inline int block_excl_scan(int v, int* s) {
    int t = threadIdx.x;
    s[t] = v;
    __syncthreads();
    for (int d = 1; d < 256; d <<= 1) {
        int x = (t >= d) ? s[t - d] : 0;
        __syncthreads();
        s[t] += x;
        __syncthreads();
    }
    return s[t] - v;   // exclusive
}

__global__ void scan1_kernel(const int* __restrict__ counts, int* __restrict__ bsum) {
    int i = blockIdx.x * 256 + threadIdx.x;
    int v = (i < N_NODES) ? counts[i] : 0;
#pragma unroll
    for (int o = 32; o > 0; o >>= 1) v += __shfl_down(v, o);
    __shared__ int s[4];
    int wave = threadIdx.x >> 6, lane = threadIdx.x & 63;
    if (lane == 0) s[wave] = v;
    __syncthreads();
    if (threadIdx.x == 0) bsum[blockIdx.x] = s[0] + s[1] + s[2] + s[3];
}

__global__ void scan2_kernel(int* __restrict__ bsum) {   // 1 block
    __shared__ int s[256];
    int t = threadIdx.x;
    int v = (t < 196) ? bsum[t] : 0;
    int excl = block_excl_scan(v, s);
    if (t < 196) bsum[t] = excl;
}

__global__ void scan3_kernel(const int* __restrict__ counts, const int* __restrict__ bsum,
                             int* __restrict__ off, int* __restrict__ cursor) {
    __shared__ int s[256];
    int i = blockIdx.x * 256 + threadIdx.x;
    int v = (i < N_NODES) ? counts[i] : 0;
    int excl = block_excl_scan(v, s) + bsum[blockIdx.x];
    if (i < N_NODES) { off[i] = excl; cursor[i] = excl; }
    if (i == N_NODES - 1) off[N_NODES] = excl + v;   // == E
}

// one interleaved int2 {tagged_src, w_bits} per edge: single 8B scattered store
__global__ void place_kernel(const int* __restrict__ ei, const float* __restrict__ ew,
                             int* __restrict__ cursor, int2* __restrict__ ep) {
    int e = blockIdx.x * blockDim.x + threadIdx.x;
    if (e < E_EDGES) {
        int src = ei[e];
        int dst = ei[E_EDGES + e];
        int pos = atomicAdd(&cursor[dst], 1);
        ep[pos] = make_int2(src | ((src == dst) ? 0x80000000 : 0),
                            __float_as_int(ew[e]));
    }
}

// ---------------------------------------------------------------- fused gather:
// BN + weighted neighbor sum + 32x32 W-contraction + relu.
// 32 lanes per node (c = lane&31), 8 nodes per 256-thread block.
__global__ void gather_kernel(const float* __restrict__ x,
                              const float* __restrict__ gamma,
                              const float* __restrict__ beta,
                              const float* __restrict__ mean,
                              const float* __restrict__ var,
                              const int*   __restrict__ off,
                              const int2*  __restrict__ ep,
                              const float* __restrict__ W,
                              float* __restrict__ rres) {
    __shared__ float s_w0[1024], s_wsum[1024];
    int tid = threadIdx.x;
    for (int idx = tid; idx < 1024; idx += 256) {
        s_w0[idx]   = W[idx];
        s_wsum[idx] = W[1024 + idx] + W[2048 + idx];
    }
    __syncthreads();

    int n     = blockIdx.x * 8 + (tid >> 5);  // 6250*8 = 50000 exactly
    int c     = tid & 31;
    int gbase = tid & 32;                     // group base lane within the wave

    float sc = gamma[c] * rsqrtf(var[c] + BN_EPS);
    float sh = beta[c] - mean[c] * sc;

    int e0 = off[n];
    int nb = off[n + 1] - e0;
    const int2* e2 = ep + e0;
    float acc = 0.f, acc0 = 0.f;

    int base = 0;
    for (; base + 32 <= nb; base += 32) {       // full batches, unmasked
        int2 p = e2[base + c];
        int sw = p.x; float wv = __int_as_float(p.y);
#pragma unroll 8
        for (int j = 0; j < 32; j++) {
            int   swj = __shfl(sw, gbase + j);
            float wj  = __shfl(wv, gbase + j);
            float v   = fmaf(x[(swj & 0x7fffffff) * 32 + c], sc, sh);
            acc = fmaf(wj, v, acc);
            if (swj < 0) acc0 += v;
        }
    }
    int rem = nb - base;
    if (rem > 0) {                               // tail batch
        int sw = 0; float wv = 0.f;
        if (c < rem) { int2 p = e2[base + c]; sw = p.x; wv = __int_as_float(p.y); }
        for (int j = 0; j < rem; j++) {
            int   swj = __shfl(sw, gbase + j);
            float wj  = __shfl(wv, gbase + j);
            float v   = fmaf(x[(swj & 0x7fffffff) * 32 + c], sc, sh);
            acc = fmaf(wj, v, acc);
            if (swj < 0) acc0 += v;
        }
    }
    float r = 0.f;
#pragma unroll
    for (int cc = 0; cc < 32; cc++) {
        float a  = __shfl(acc,  gbase + cc);
        float a0 = __shfl(acc0, gbase + cc);
        r = fmaf(a,  s_wsum[cc * 32 + c], r);
        r = fmaf(a0, s_w0  [cc * 32 + c], r);
    }
    rres[n * 32 + c] = fmaxf(r, 0.f);
}

// ---------------------------------------------------------------- fc1: [1,NH] @ [NH,64]^T
// r2's best shape (625 blocks, 4 waves, 16 rows/wave, LDS r-stage) but
// ATOMIC-FREE: each block writes its 64 partial sums to a private 256B slot.
// (40000 same-line fp32 atomics were backpressuring the whole memory pipe.)
constexpr int CHUNK = 2560;   // 640 float4; NH/CHUNK = 625
__global__ void fc1_kernel(const float* __restrict__ r,
                           const float* __restrict__ w,
                           float* __restrict__ partial) {
    __shared__ float4 s_r[640];
    int tid = threadIdx.x;
    size_t ib = (size_t)blockIdx.x * CHUNK;
    const float4* r4 = (const float4*)(r + ib);
    for (int i = tid; i < 640; i += 256) s_r[i] = r4[i];
    __syncthreads();

    int wave = tid >> 6, lane = tid & 63;
    int jbase = wave * 16;
    float* pout = partial + blockIdx.x * 64;
    for (int jj = 0; jj < 16; jj += 2) {
        const float4* wa = (const float4*)(w + (size_t)(jbase + jj    ) * NH + ib);
        const float4* wb = (const float4*)(w + (size_t)(jbase + jj + 1) * NH + ib);
        float a0 = 0.f, a1 = 0.f;
#pragma unroll
        for (int k = 0; k < 10; k++) {
            float4 rv = s_r[lane + k * 64];
            float4 x0 = wa[lane + k * 64];
            float4 x1 = wb[lane + k * 64];
            a0 = fmaf(rv.x, x0.x, a0); a0 = fmaf(rv.y, x0.y, a0);
            a0 = fmaf(rv.z, x0.z, a0); a0 = fmaf(rv.w, x0.w, a0);
            a1 = fmaf(rv.x, x1.x, a1); a1 = fmaf(rv.y, x1.y, a1);
            a1 = fmaf(rv.z, x1.z, a1); a1 = fmaf(rv.w, x1.w, a1);
        }
#pragma unroll
        for (int o = 32; o > 0; o >>= 1) {
            a0 += __shfl_down(a0, o);
            a1 += __shfl_down(a1, o);
        }
        if (lane == 0) {
            pout[jbase + jj    ] = a0;   // plain store, distinct address per block
            pout[jbase + jj + 1] = a1;
        }
    }
}

// ---------------------------------------------------------------- reduce + head
// 1 block x 1024 threads: sum partial[625][64] (16 slices of 64), then
// bias + relu + fc2 on wave 0. Replaces hacc atomics + head_kernel.
__global__ void reduce_head_kernel(const float* __restrict__ partial,
                                   const float* __restrict__ fc1_b,
                                   const float* __restrict__ fc2_w,
                                   const float* __restrict__ fc2_b,
                                   float* __restrict__ out) {
    __shared__ float red[1024];
    int t = threadIdx.x;
    int j = t & 63, s = t >> 6;          // 16 slices over 625 blocks
    float a = 0.f;
    for (int b = s; b < NBLK; b += 16) a += partial[b * 64 + j];  // coalesced
    red[t] = a;
    __syncthreads();
    if (s == 0) {
        float h = fc1_b[j];
#pragma unroll
        for (int q = 0; q < 16; q++) h += red[q * 64 + j];
        h = fmaxf(h, 0.f);
#pragma unroll
        for (int k = 0; k < 2; k++) {
            float p = h * fc2_w[k * 64 + j];
#pragma unroll
            for (int o = 32; o > 0; o >>= 1) p += __shfl_down(p, o);
            if (j == 0) out[k] = p + fc2_b[k];
        }
    }
}

// ---------------------------------------------------------------- launch
extern "C" void kernel_launch(void* const* d_in, const int* in_sizes, int n_in,
                              void* d_out, int out_size, void* d_ws, size_t ws_size,
                              hipStream_t stream) {
    const float* x     = (const float*)d_in[0];
    const float* ew    = (const float*)d_in[1];
    const float* W     = (const float*)d_in[2];
    const float* gamma = (const float*)d_in[3];
    const float* beta  = (const float*)d_in[4];
    const float* mean  = (const float*)d_in[5];
    const float* var   = (const float*)d_in[6];
    const float* fc1_w = (const float*)d_in[7];
    const float* fc1_b = (const float*)d_in[8];
    const float* fc2_w = (const float*)d_in[9];
    const float* fc2_b = (const float*)d_in[10];
    const int*   ei    = (const int*)d_in[11];
    float* out = (float*)d_out;

    // ws layout (4B elems): partial(625*64=40000) | counts(NPAD) | off(NPAD)
    //   | cursor(NPAD) | bsum(256) | ep(int2 x E) | rres(NH)   ~ 20 MB
    float* partial = (float*)d_ws;
    int*   counts  = (int*)d_ws + 40000;
    int*   off     = (int*)d_ws + 40000 + NPAD;
    int*   cursor  = (int*)d_ws + 40000 + 2 * NPAD;
    int*   bsum    = (int*)d_ws + 40000 + 3 * NPAD;
    int2*  ep      = (int2*)(bsum + 256);       // 8B-aligned
    float* rres    = (float*)(ep + E_EDGES);
    (void)ws_size; (void)in_sizes; (void)n_in; (void)out_size;

    {   // zero counts only (partial fully overwritten by fc1 every call)
        int n4 = NPAD / 4;
        zero_kernel<<<(n4 + 255) / 256, 256, 0, stream>>>((float4*)counts, n4);
    }
    hist_kernel <<<(E_EDGES + 255) / 256, 256, 0, stream>>>(ei, counts);
    scan1_kernel<<<196, 256, 0, stream>>>(counts, bsum);
    scan2_kernel<<<1,   256, 0, stream>>>(bsum);
    scan3_kernel<<<196, 256, 0, stream>>>(counts, bsum, off, cursor);
    place_kernel<<<(E_EDGES + 255) / 256, 256, 0, stream>>>(ei, ew, cursor, ep);
    gather_kernel<<<N_NODES / 8, 256, 0, stream>>>(x, gamma, beta, mean, var,
                                                   off, ep, W, rres);
    fc1_kernel <<<NBLK, 256, 0, stream>>>(rres, fc1_w, partial);
    reduce_head_kernel<<<1, 1024, 0, stream>>>(partial, fc1_b, fc2_w, fc2_b, out);
}